// Round 9
// baseline (178.521 us; speedup 1.0000x reference)
//
#include <hip/hip_runtime.h>
#include <cstdint>
#include <cstddef>

// Problem constants
#define Bb   64
#define Ll   2048
#define Mm   128
#define ROWS (Bb * Ll)          // 131072
#define OUTC 768                // 6*M
#define LDF  132                // epilogue LDS stride (f32 elems)

typedef __attribute__((ext_vector_type(4))) float  f32x4;
typedef __attribute__((ext_vector_type(8))) short  bf16x8;   // storage for 8 bf16
typedef __bf16 bf16x8b __attribute__((ext_vector_type(8)));  // builtin operand type

__device__ __forceinline__ float rcp_(float x) {
#if __has_builtin(__builtin_amdgcn_rcpf)
    return __builtin_amdgcn_rcpf(x);
#else
    return 1.0f / x;
#endif
}
__device__ __forceinline__ float sigmoid_(float x) {
    return rcp_(1.0f + __expf(-x));
}
__device__ __forceinline__ float tanh_(float x) {
    float ax = fabsf(x);
    float r  = __expf(-2.0f * ax);
    float t  = (1.0f - r) * rcp_(1.0f + r);
    return x < 0.0f ? -t : t;
}
// f32 -> bf16 bits (RNE) for the once-only W prep
__device__ __forceinline__ short f2bf(float f) {
    uint32_t u = __builtin_bit_cast(uint32_t, f);
    u = (u + 0x7FFFu + ((u >> 16) & 1u)) >> 16;
    return (short)(u & 0xFFFFu);
}

// LDS-only barrier (composable_kernel block_sync_lds pattern): waits LDS ops,
// does NOT drain vmcnt -> global stores + loads stay in flight.
__device__ __forceinline__ void lds_sync() {
    asm volatile("s_waitcnt lgkmcnt(0)\n\ts_barrier" ::: "memory");
}

// ---------------------------------------------------------------------------
// ws layout:
//   floats [0 .. 32768)     : state: [0]=cph,[1]=cpc,[2]=hph,[3]=hpc (64,128)
//   shorts [65536 .. 98304) : Wbf [gate*128+col][k] bf16, gate 0=Wc 1=Wo
// ---------------------------------------------------------------------------

// Kernel 1: collapsed tree state. Wi/Wf/Wu columns preloaded to registers;
// k-split 4-way across 512 threads with LDS partial reduction; wprep fused.
__global__ __launch_bounds__(512)
void state_kernel(const float* __restrict__ root_c, const float* __restrict__ root_h,
                  const float* __restrict__ Wi, const float* __restrict__ bi,
                  const float* __restrict__ Wf, const float* __restrict__ bfv,
                  const float* __restrict__ Wu, const float* __restrict__ bu,
                  const float* __restrict__ Wc, const float* __restrict__ bc,
                  const float* __restrict__ Wo, const float* __restrict__ bo,
                  float* __restrict__ ws, short* __restrict__ wbf)
{
    const int b   = blockIdx.x;
    const int tid = threadIdx.x;
    const int m   = tid & 127;
    const int q   = tid >> 7;            // 0..3
    const int k0  = q * 32;

    __shared__ float h_sh[Mm];
    __shared__ float c_sh[Mm];
    __shared__ float part[4][4][Mm];     // [slot][q][m]

    // fused wprep: 64 blocks x 512 threads = 32768 elems, 1 per thread
    {
        int idx  = b * 512 + tid;
        int gate = idx >> 14;
        int col  = (idx >> 7) & 127;
        int k    = idx & 127;
        const float* W = gate ? Wo : Wc;
        wbf[idx] = f2bf(W[k * Mm + col]);
    }

    // preload my k-slice of Wi/Wf/Wu columns (coalesced across m)
    float wi[32], wf[32], wu[32];
    #pragma unroll
    for (int kk = 0; kk < 32; ++kk) {
        wi[kk] = Wi[(k0 + kk) * Mm + m];
        wf[kk] = Wf[(k0 + kk) * Mm + m];
        wu[kk] = Wu[(k0 + kk) * Mm + m];
    }

    float c = 0.f;
    if (q == 0) {
        c = root_c[b * Mm + m];
        h_sh[m] = root_h[b * Mm + m];
    }
    __syncthreads();

    const float bi_m = bi[m], bf_m = bfv[m], bu_m = bu[m];

    for (int it = 0; it < 10; ++it) {        // depth-1 = 10
        float di0 = 0.f, di1 = 0.f, df0 = 0.f, df1 = 0.f, du0 = 0.f, du1 = 0.f;
        #pragma unroll
        for (int kk = 0; kk < 32; kk += 2) {
            float h0 = h_sh[k0 + kk], h1 = h_sh[k0 + kk + 1];
            di0 = fmaf(h0, wi[kk], di0);
            di1 = fmaf(h1, wi[kk + 1], di1);
            df0 = fmaf(h0, wf[kk], df0);
            df1 = fmaf(h1, wf[kk + 1], df1);
            du0 = fmaf(h0, wu[kk], du0);
            du1 = fmaf(h1, wu[kk + 1], du1);
        }
        part[0][q][m] = di0 + di1;
        part[1][q][m] = df0 + df1;
        part[2][q][m] = du0 + du1;
        __syncthreads();
        if (q == 0) {
            float di = (part[0][0][m] + part[0][1][m]) + (part[0][2][m] + part[0][3][m]);
            float df = (part[1][0][m] + part[1][1][m]) + (part[1][2][m] + part[1][3][m]);
            float du = (part[2][0][m] + part[2][1][m]) + (part[2][2][m] + part[2][3][m]);
            float ig = sigmoid_(di + bi_m);
            float fg = sigmoid_(df + bf_m);
            float ug = tanh_(du + bu_m);
            c = ig * ug + fg * c;
            h_sh[m] = tanh_(c);
        }
        __syncthreads();
    }
    if (q == 0) c_sh[m] = c;
    __syncthreads();

    // leaf on final h and c states, k-split
    float dch = 0.f, doh = 0.f, dcc = 0.f, doc = 0.f;
    #pragma unroll
    for (int kk = 0; kk < 32; ++kk) {
        int k = k0 + kk;
        float hk = h_sh[k], ck = c_sh[k];
        float wc = Wc[k * Mm + m], wo = Wo[k * Mm + m];
        dch = fmaf(hk, wc, dch);
        doh = fmaf(hk, wo, doh);
        dcc = fmaf(ck, wc, dcc);
        doc = fmaf(ck, wo, doc);
    }
    part[0][q][m] = dch;
    part[1][q][m] = doh;
    part[2][q][m] = dcc;
    part[3][q][m] = doc;
    __syncthreads();
    if (q == 0) {
        float Dch = (part[0][0][m] + part[0][1][m]) + (part[0][2][m] + part[0][3][m]);
        float Doh = (part[1][0][m] + part[1][1][m]) + (part[1][2][m] + part[1][3][m]);
        float Dcc = (part[2][0][m] + part[2][1][m]) + (part[2][2][m] + part[2][3][m]);
        float Doc = (part[3][0][m] + part[3][1][m]) + (part[3][2][m] + part[3][3][m]);
        const float bcm = bc[m], bom = bo[m];
        float cph = Dch + bcm;
        float cpc = Dcc + bcm;
        float hph = sigmoid_(Doh + bom) * tanh_(cph);
        float hpc = sigmoid_(Doc + bom) * tanh_(cpc);
        ws[0 * Bb * Mm + b * Mm + m] = cph;
        ws[1 * Bb * Mm + b * Mm + m] = cpc;
        ws[2 * Bb * Mm + b * Mm + m] = hph;
        ws[3 * Bb * Mm + b * Mm + m] = hpc;
    }
}

// ---------------------------------------------------------------------------
// Kernel 2 (v7 = R7 minus A-staging): A-fragments load DIRECTLY from global
// (lane (g,ln) reads embs[rt*16+ln][ks*32+g*8..+8] = 32B contiguous, 2xf32x4),
// converted via compiler (__bf16) casts (v_cvt_pk). No A-LDS, no staging
// barriers, no stage registers, no prologue — each wave's read+MFMA phase is
// fully independent; only the epilogue transpose syncs (lgkm-only). The 8x
// tile re-read hits L1/L2 (plain loads, 64KB tile); HBM traffic unchanged.
// Epilogue identical to R7 (best-known store pattern).
// ---------------------------------------------------------------------------
__global__ __launch_bounds__(512, 4)
void fused_kernel(const float* __restrict__ embs,
                  const short* __restrict__ wbf,
                  const float* __restrict__ bc, const float* __restrict__ bo,
                  const float* __restrict__ state,
                  float* __restrict__ out)
{
    __shared__ float ce_l[32 * LDF];      // 16896 B
    __shared__ float he_l[32 * LDF];      // 16896 B
    __shared__ float st_l[512];           //  2048 B

    const int tid  = threadIdx.x;
    const int w    = tid >> 6;          // wave 0..7
    const int lane = tid & 63;
    const int g    = lane >> 4;         // lane group 0..3 (k-chunk)
    const int ln   = lane & 15;
    const int n0   = w * 16 + ln;       // output col 0..127
    const int rowbase0 = blockIdx.x * 128;
    const int b        = rowbase0 >> 11;   // 128 | 2048, never spans batches

    // --- B fragments + biases + state stash ---------------------------------
    bf16x8 bfrag[2][4];                 // [gate][ks], k = ks*32 + g*8 + j
    #pragma unroll
    for (int gate = 0; gate < 2; ++gate)
        #pragma unroll
        for (int ks = 0; ks < 4; ++ks)
            bfrag[gate][ks] = *(const bf16x8*)(
                wbf + gate * (Mm * Mm) + n0 * Mm + ks * 32 + g * 8);
    const float biasc = bc[n0];
    const float biaso = bo[n0];
    st_l[tid] = state[(tid >> 7) * (Bb * Mm) + b * Mm + (tid & 127)];
    // st_l ordered vs epilogue reads by the epilogue's first lds_sync.

    // epilogue: D layout col = lane&15 (= n0), row = 4*(lane>>4) + reg;
    // unified full-row writes: every row's 3KB stored once, ascending order.
    auto epilogue = [&](int rowbase, f32x4 (&acc)[4][2]) {
        #pragma unroll
        for (int half = 0; half < 2; ++half) {
            #pragma unroll
            for (int qq = 0; qq < 2; ++qq) {
                int rt = half * 2 + qq;
                #pragma unroll
                for (int r = 0; r < 4; ++r) {
                    int rowL = qq * 16 + g * 4 + r;      // 0..31 in this half
                    float cv = acc[rt][0][r];
                    float hv = sigmoid_(acc[rt][1][r]) * tanh_(cv);
                    ce_l[rowL * LDF + n0] = cv;
                    he_l[rowL * LDF + n0] = hv;
                }
            }
            lds_sync();
            // 32 rows x 192 f32x4 = 6144 units; 12/thread; lanes contiguous
            #pragma unroll
            for (int i = 0; i < 12; ++i) {
                int u  = tid + 512 * i;
                int rg = u / 192;
                int s  = u - rg * 192;      // f32x4 col in row, 0..191
                int sec = s >> 5;           // 0:ce 1:cph 2:cpc 3:he 4:hph 5:hpc
                int cc  = s & 31;
                const float* src =
                    (sec == 0) ? (ce_l + rg * LDF + cc * 4) :
                    (sec == 3) ? (he_l + rg * LDF + cc * 4) :
                    (st_l + ((sec < 3) ? (sec - 1) : (sec - 2)) * 128 + cc * 4);
                f32x4 v = *(const f32x4*)src;
                *(f32x4*)(out + (size_t)(rowbase + half * 32 + rg) * OUTC + s * 4) = v;
            }
            lds_sync();                     // LDS reads done before reuse
        }
    };

    // per-lane A base: row (.. + ln), k-offset g*8
    const float* abase = embs + (size_t)(rowbase0 + ln) * Mm + g * 8;

    #pragma unroll
    for (int t = 0; t < 2; ++t) {
        const int rowbase = rowbase0 + t * 64;

        f32x4 acc[4][2];                    // [rt][gate], bias-initialized
        #pragma unroll
        for (int rt = 0; rt < 4; ++rt)
            #pragma unroll
            for (int gate = 0; gate < 2; ++gate) {
                float bv = gate ? biaso : biasc;
                acc[rt][gate][0] = bv; acc[rt][gate][1] = bv;
                acc[rt][gate][2] = bv; acc[rt][gate][3] = bv;
            }

        #pragma unroll
        for (int ks = 0; ks < 4; ++ks) {
            bf16x8b af[4];
            #pragma unroll
            for (int rt = 0; rt < 4; ++rt) {
                const float* ap = abase + (size_t)(t * 64 + rt * 16) * Mm + ks * 32;
                f32x4 a0 = *(const f32x4*)ap;
                f32x4 a1 = *(const f32x4*)(ap + 4);
                bf16x8b f;
                f[0] = (__bf16)a0[0]; f[1] = (__bf16)a0[1];
                f[2] = (__bf16)a0[2]; f[3] = (__bf16)a0[3];
                f[4] = (__bf16)a1[0]; f[5] = (__bf16)a1[1];
                f[6] = (__bf16)a1[2]; f[7] = (__bf16)a1[3];
                af[rt] = f;
            }
            #pragma unroll
            for (int rt = 0; rt < 4; ++rt)
                #pragma unroll
                for (int gate = 0; gate < 2; ++gate)
                    acc[rt][gate] = __builtin_amdgcn_mfma_f32_16x16x32_bf16(
                        af[rt],
                        __builtin_bit_cast(bf16x8b, bfrag[gate][ks]),
                        acc[rt][gate], 0, 0, 0);
        }

        epilogue(rowbase, acc);
    }
}

extern "C" void kernel_launch(void* const* d_in, const int* in_sizes, int n_in,
                              void* d_out, int out_size, void* d_ws, size_t ws_size,
                              hipStream_t stream) {
    const float* embs   = (const float*)d_in[0];
    const float* root_c = (const float*)d_in[1];
    const float* root_h = (const float*)d_in[2];
    const float* Wi = (const float*)d_in[3];
    const float* bi = (const float*)d_in[4];
    const float* Wf = (const float*)d_in[5];
    const float* bfv= (const float*)d_in[6];
    const float* Wu = (const float*)d_in[7];
    const float* bu = (const float*)d_in[8];
    const float* Wc = (const float*)d_in[9];
    const float* bc = (const float*)d_in[10];
    const float* Wo = (const float*)d_in[11];
    const float* bo = (const float*)d_in[12];

    float* out   = (float*)d_out;
    float* state = (float*)d_ws;                       // 128 KB
    short* wbf   = (short*)d_ws + 65536;               // 64 KB bf16 W

    state_kernel<<<dim3(Bb), dim3(512), 0, stream>>>(
        root_c, root_h, Wi, bi, Wf, bfv, Wu, bu, Wc, bc, Wo, bo, state, wbf);
    fused_kernel<<<dim3(1024), dim3(512), 0, stream>>>(
        embs, wbf, bc, bo, state, out);
}

// Round 10
// 115.641 us; speedup vs baseline: 1.5437x; 1.5437x over previous
//
#include <hip/hip_runtime.h>
#include <cstdint>
#include <cstddef>

// Problem constants
#define Bb   64
#define Ll   2048
#define Mm   128
#define ROWS (Bb * Ll)          // 131072
#define OUTC 768                // 6*M
#define LDA  136                // A-stage LDS stride (bf16 elems)
#define LDF  132                // epilogue LDS stride (f32 elems)

typedef __attribute__((ext_vector_type(4))) float  f32x4;
typedef __attribute__((ext_vector_type(8))) short  bf16x8;   // storage for 8 bf16
typedef __attribute__((ext_vector_type(4))) short  short4v;
typedef __bf16 bf16x8b __attribute__((ext_vector_type(8)));  // builtin operand type

__device__ __forceinline__ float rcp_(float x) {
#if __has_builtin(__builtin_amdgcn_rcpf)
    return __builtin_amdgcn_rcpf(x);
#else
    return 1.0f / x;
#endif
}
__device__ __forceinline__ float sigmoid_(float x) {
    return rcp_(1.0f + __expf(-x));
}
__device__ __forceinline__ float tanh_(float x) {
    float ax = fabsf(x);
    float r  = __expf(-2.0f * ax);
    float t  = (1.0f - r) * rcp_(1.0f + r);
    return x < 0.0f ? -t : t;
}
// f32 -> bf16 bits, round-to-nearest-even
__device__ __forceinline__ short f2bf(float f) {
    uint32_t u = __builtin_bit_cast(uint32_t, f);
    u = (u + 0x7FFFu + ((u >> 16) & 1u)) >> 16;
    return (short)(u & 0xFFFFu);
}

// LDS-only barrier (composable_kernel block_sync_lds pattern): waits LDS ops,
// does NOT drain vmcnt -> global stores + prefetch loads stay in flight.
__device__ __forceinline__ void lds_sync() {
    asm volatile("s_waitcnt lgkmcnt(0)\n\ts_barrier" ::: "memory");
}

// ---------------------------------------------------------------------------
// ws layout:
//   floats [0 .. 32768)     : state: [0]=cph,[1]=cpc,[2]=hph,[3]=hpc (64,128)
//   shorts [65536 .. 98304) : Wbf [gate*128+col][k] bf16, gate 0=Wc 1=Wo
// ---------------------------------------------------------------------------

// Kernel 1: collapsed tree state. Wi/Wf/Wu columns preloaded to registers;
// k-split 4-way across 512 threads with LDS partial reduction; wprep fused.
__global__ __launch_bounds__(512)
void state_kernel(const float* __restrict__ root_c, const float* __restrict__ root_h,
                  const float* __restrict__ Wi, const float* __restrict__ bi,
                  const float* __restrict__ Wf, const float* __restrict__ bfv,
                  const float* __restrict__ Wu, const float* __restrict__ bu,
                  const float* __restrict__ Wc, const float* __restrict__ bc,
                  const float* __restrict__ Wo, const float* __restrict__ bo,
                  float* __restrict__ ws, short* __restrict__ wbf)
{
    const int b   = blockIdx.x;
    const int tid = threadIdx.x;
    const int m   = tid & 127;
    const int q   = tid >> 7;            // 0..3
    const int k0  = q * 32;

    __shared__ float h_sh[Mm];
    __shared__ float c_sh[Mm];
    __shared__ float part[4][4][Mm];     // [slot][q][m]

    // fused wprep: 64 blocks x 512 threads = 32768 elems, 1 per thread
    {
        int idx  = b * 512 + tid;
        int gate = idx >> 14;
        int col  = (idx >> 7) & 127;
        int k    = idx & 127;
        const float* W = gate ? Wo : Wc;
        wbf[idx] = f2bf(W[k * Mm + col]);
    }

    // preload my k-slice of Wi/Wf/Wu columns (coalesced across m)
    float wi[32], wf[32], wu[32];
    #pragma unroll
    for (int kk = 0; kk < 32; ++kk) {
        wi[kk] = Wi[(k0 + kk) * Mm + m];
        wf[kk] = Wf[(k0 + kk) * Mm + m];
        wu[kk] = Wu[(k0 + kk) * Mm + m];
    }

    float c = 0.f;
    if (q == 0) {
        c = root_c[b * Mm + m];
        h_sh[m] = root_h[b * Mm + m];
    }
    __syncthreads();

    const float bi_m = bi[m], bf_m = bfv[m], bu_m = bu[m];

    for (int it = 0; it < 10; ++it) {        // depth-1 = 10
        float di0 = 0.f, di1 = 0.f, df0 = 0.f, df1 = 0.f, du0 = 0.f, du1 = 0.f;
        #pragma unroll
        for (int kk = 0; kk < 32; kk += 2) {
            float h0 = h_sh[k0 + kk], h1 = h_sh[k0 + kk + 1];
            di0 = fmaf(h0, wi[kk], di0);
            di1 = fmaf(h1, wi[kk + 1], di1);
            df0 = fmaf(h0, wf[kk], df0);
            df1 = fmaf(h1, wf[kk + 1], df1);
            du0 = fmaf(h0, wu[kk], du0);
            du1 = fmaf(h1, wu[kk + 1], du1);
        }
        part[0][q][m] = di0 + di1;
        part[1][q][m] = df0 + df1;
        part[2][q][m] = du0 + du1;
        __syncthreads();
        if (q == 0) {
            float di = (part[0][0][m] + part[0][1][m]) + (part[0][2][m] + part[0][3][m]);
            float df = (part[1][0][m] + part[1][1][m]) + (part[1][2][m] + part[1][3][m]);
            float du = (part[2][0][m] + part[2][1][m]) + (part[2][2][m] + part[2][3][m]);
            float ig = sigmoid_(di + bi_m);
            float fg = sigmoid_(df + bf_m);
            float ug = tanh_(du + bu_m);
            c = ig * ug + fg * c;
            h_sh[m] = tanh_(c);
        }
        __syncthreads();
    }
    if (q == 0) c_sh[m] = c;
    __syncthreads();

    // leaf on final h and c states, k-split
    float dch = 0.f, doh = 0.f, dcc = 0.f, doc = 0.f;
    #pragma unroll
    for (int kk = 0; kk < 32; ++kk) {
        int k = k0 + kk;
        float hk = h_sh[k], ck = c_sh[k];
        float wc = Wc[k * Mm + m], wo = Wo[k * Mm + m];
        dch = fmaf(hk, wc, dch);
        doh = fmaf(hk, wo, doh);
        dcc = fmaf(ck, wc, dcc);
        doc = fmaf(ck, wo, doc);
    }
    part[0][q][m] = dch;
    part[1][q][m] = doh;
    part[2][q][m] = dcc;
    part[3][q][m] = doc;
    __syncthreads();
    if (q == 0) {
        float Dch = (part[0][0][m] + part[0][1][m]) + (part[0][2][m] + part[0][3][m]);
        float Doh = (part[1][0][m] + part[1][1][m]) + (part[1][2][m] + part[1][3][m]);
        float Dcc = (part[2][0][m] + part[2][1][m]) + (part[2][2][m] + part[2][3][m]);
        float Doc = (part[3][0][m] + part[3][1][m]) + (part[3][2][m] + part[3][3][m]);
        const float bcm = bc[m], bom = bo[m];
        float cph = Dch + bcm;
        float cpc = Dcc + bcm;
        float hph = sigmoid_(Doh + bom) * tanh_(cph);
        float hpc = sigmoid_(Doc + bom) * tanh_(cpc);
        ws[0 * Bb * Mm + b * Mm + m] = cph;
        ws[1 * Bb * Mm + b * Mm + m] = cpc;
        ws[2 * Bb * Mm + b * Mm + m] = hph;
        ws[3 * Bb * Mm + b * Mm + m] = hpc;
    }
}

// ---------------------------------------------------------------------------
// Kernel 2 (v8 = R7 algorithm, fine-granularity tiling):
// 2048 blocks x 256 thr (4-wave gangs), 2 tiles of 32 rows each, double-
// buffered A, ~36KB LDS -> 4 blocks/CU resident (16 waves/CU, 2x independent
// barrier gangs vs R7's 8-wave pairs). Each wave covers 2 col-groups
// (ct loop; bfrag reloaded per ct from L2-hot wbf -> peak VGPR ~105, no
// spill). Epilogue: 16-row halves, unified full-row contiguous stores.
// ---------------------------------------------------------------------------
__global__ __launch_bounds__(256, 4)
void fused_kernel(const float* __restrict__ embs,
                  const short* __restrict__ wbf,
                  const float* __restrict__ bc, const float* __restrict__ bo,
                  const float* __restrict__ state,
                  float* __restrict__ out)
{
    // A0[32][LDA] | A1[32][LDA] (bf16) | ce[16][LDF] | he[16][LDF] (f32) | st[512]
    __shared__ __align__(16) char smem[36352];
    short* A0   = (short*)smem;                    //  8704 B
    short* A1   = (short*)(smem +  8704);          //  8704 B
    float* ce_l = (float*)(smem + 17408);          //  8448 B
    float* he_l = (float*)(smem + 25856);          //  8448 B
    float* st_l = (float*)(smem + 34304);          //  2048 B

    const int tid  = threadIdx.x;
    const int w    = tid >> 6;          // wave 0..3
    const int lane = tid & 63;
    const int g    = lane >> 4;         // lane group 0..3
    const int ln   = lane & 15;
    const int rows0 = blockIdx.x * 64;  // 2 tiles x 32 rows
    const int b     = rows0 >> 11;      // 64 | 2048: never spans batches

    // --- biases + state stash ----------------------------------------------
    float biasc[2], biaso[2];
    #pragma unroll
    for (int ct = 0; ct < 2; ++ct) {
        int n0 = ct * 64 + w * 16 + ln;
        biasc[ct] = bc[n0];
        biaso[ct] = bo[n0];
    }
    st_l[tid]       = state[0 * (Bb * Mm) + b * Mm + (tid & 127) + 0];
    st_l[tid + 256] = state[2 * (Bb * Mm) + b * Mm + (tid & 127) + 0];
    // layout note: st_l[0..128)=cph st_l[128..256)=cpc st_l[256..384)=hph
    // st_l[384..512)=hpc  (tid>>7 selects second half of each pair)
    // (state rows are 128 floats; tid 0..255 covers cph|cpc, +256 covers hph|hpc)

    // helpers ---------------------------------------------------------------
    auto stage_load = [&](int rowbase, f32x4 (&r)[4]) {
        #pragma unroll
        for (int i = 0; i < 4; ++i) {
            int idx = tid + 256 * i;            // 0..1023 float4-slots
            int rr  = idx >> 5;                 // 32 slots per row
            int kq  = idx & 31;
            r[i] = __builtin_nontemporal_load(
                (const f32x4*)(embs + (size_t)(rowbase + rr) * Mm + kq * 4));
        }
    };
    auto stage_write = [&](short* A, const f32x4 (&r)[4]) {
        #pragma unroll
        for (int i = 0; i < 4; ++i) {
            int idx = tid + 256 * i;
            int rr  = idx >> 5;
            int kq  = idx & 31;
            short4v s4;
            s4[0] = f2bf(r[i][0]); s4[1] = f2bf(r[i][1]);
            s4[2] = f2bf(r[i][2]); s4[3] = f2bf(r[i][3]);
            *(short4v*)(&A[rr * LDA + kq * 4]) = s4;
        }
    };
    // MFMA for one tile: acc[rt(2)][ct(2)][gate(2)]; bfrag loaded per ct.
    auto do_mfma = [&](const short* A, f32x4 (&acc)[2][2][2]) {
        #pragma unroll
        for (int ct = 0; ct < 2; ++ct) {
            const int n0 = ct * 64 + w * 16 + ln;
            bf16x8 bfrag[2][4];         // [gate][ks]
            #pragma unroll
            for (int gate = 0; gate < 2; ++gate)
                #pragma unroll
                for (int ks = 0; ks < 4; ++ks)
                    bfrag[gate][ks] = *(const bf16x8*)(
                        wbf + gate * (Mm * Mm) + n0 * Mm + ks * 32 + g * 8);
            #pragma unroll
            for (int rt = 0; rt < 2; ++rt)
                #pragma unroll
                for (int gate = 0; gate < 2; ++gate) {
                    float bv = gate ? biaso[ct] : biasc[ct];
                    acc[rt][ct][gate][0] = bv; acc[rt][ct][gate][1] = bv;
                    acc[rt][ct][gate][2] = bv; acc[rt][ct][gate][3] = bv;
                }
            #pragma unroll
            for (int ks = 0; ks < 4; ++ks) {
                bf16x8 af[2];
                #pragma unroll
                for (int rt = 0; rt < 2; ++rt)
                    af[rt] = *(const bf16x8*)(&A[(rt * 16 + ln) * LDA + ks * 32 + g * 8]);
                #pragma unroll
                for (int rt = 0; rt < 2; ++rt)
                    #pragma unroll
                    for (int gate = 0; gate < 2; ++gate)
                        acc[rt][ct][gate] = __builtin_amdgcn_mfma_f32_16x16x32_bf16(
                            __builtin_bit_cast(bf16x8b, af[rt]),
                            __builtin_bit_cast(bf16x8b, bfrag[gate][ks]),
                            acc[rt][ct][gate], 0, 0, 0);
            }
        }
    };
    // epilogue: D layout col = lane&15, row = 4*(lane>>4)+reg. 16-row halves;
    // unified full-row writes (each row's 3KB stored once, ascending).
    auto epilogue = [&](int rowbase, f32x4 (&acc)[2][2][2]) {
        #pragma unroll
        for (int half = 0; half < 2; ++half) {
            #pragma unroll
            for (int ct = 0; ct < 2; ++ct) {
                const int n0 = ct * 64 + w * 16 + ln;
                #pragma unroll
                for (int r = 0; r < 4; ++r) {
                    int rowL = g * 4 + r;                // 0..15 in this half
                    float cv = acc[half][ct][0][r];
                    float hv = sigmoid_(acc[half][ct][1][r]) * tanh_(cv);
                    ce_l[rowL * LDF + n0] = cv;
                    he_l[rowL * LDF + n0] = hv;
                }
            }
            lds_sync();
            // 16 rows x 192 f32x4 = 3072 units; 12/thread; lanes contiguous
            #pragma unroll
            for (int i = 0; i < 12; ++i) {
                int u  = tid + 256 * i;
                int rg = u / 192;
                int s  = u - rg * 192;      // f32x4 col in row, 0..191
                int sec = s >> 5;           // 0:ce 1:cph 2:cpc 3:he 4:hph 5:hpc
                int cc  = s & 31;
                const float* src =
                    (sec == 0) ? (ce_l + rg * LDF + cc * 4) :
                    (sec == 3) ? (he_l + rg * LDF + cc * 4) :
                    (st_l + ((sec < 3) ? (sec - 1) : (sec - 2)) * 128 + cc * 4);
                f32x4 v = *(const f32x4*)src;
                *(f32x4*)(out + (size_t)(rowbase + half * 16 + rg) * OUTC + s * 4) = v;
            }
            lds_sync();                     // LDS reads done before reuse
        }
    };

    // --- pipeline: 2 tiles, prefetch t1 under t0 compute --------------------
    f32x4 r[4];
    f32x4 acc[2][2][2];

    stage_load(rows0, r);
    stage_write(A0, r);
    lds_sync();                             // A0 visible

    stage_load(rows0 + 32, r);              // t1 loads in flight under t0 work

    do_mfma(A0, acc);
    stage_write(A1, r);                     // reg-use vmcnt wait sits here
    lds_sync();                             // A0 reads done; A1 visible

    epilogue(rows0, acc);
    do_mfma(A1, acc);
    epilogue(rows0 + 32, acc);
}

extern "C" void kernel_launch(void* const* d_in, const int* in_sizes, int n_in,
                              void* d_out, int out_size, void* d_ws, size_t ws_size,
                              hipStream_t stream) {
    const float* embs   = (const float*)d_in[0];
    const float* root_c = (const float*)d_in[1];
    const float* root_h = (const float*)d_in[2];
    const float* Wi = (const float*)d_in[3];
    const float* bi = (const float*)d_in[4];
    const float* Wf = (const float*)d_in[5];
    const float* bfv= (const float*)d_in[6];
    const float* Wu = (const float*)d_in[7];
    const float* bu = (const float*)d_in[8];
    const float* Wc = (const float*)d_in[9];
    const float* bc = (const float*)d_in[10];
    const float* Wo = (const float*)d_in[11];
    const float* bo = (const float*)d_in[12];

    float* out   = (float*)d_out;
    float* state = (float*)d_ws;                       // 128 KB
    short* wbf   = (short*)d_ws + 65536;               // 64 KB bf16 W

    state_kernel<<<dim3(Bb), dim3(512), 0, stream>>>(
        root_c, root_h, Wi, bi, Wf, bfv, Wu, bu, Wc, bc, Wo, bo, state, wbf);
    fused_kernel<<<dim3(2048), dim3(256), 0, stream>>>(
        embs, wbf, bc, bo, state, out);
}

// Round 11
// 109.977 us; speedup vs baseline: 1.6233x; 1.0515x over previous
//
#include <hip/hip_runtime.h>
#include <cstdint>
#include <cstddef>

// Problem constants
#define Bb   64
#define Ll   2048
#define Mm   128
#define ROWS (Bb * Ll)          // 131072
#define OUTC 768                // 6*M
#define LDA  136                // A-stage LDS stride (bf16 elems)
#define LDF  132                // epilogue LDS stride (f32 elems)

typedef __attribute__((ext_vector_type(4))) float  f32x4;
typedef __attribute__((ext_vector_type(8))) short  bf16x8;   // storage for 8 bf16
typedef __attribute__((ext_vector_type(4))) short  short4v;
typedef __bf16 bf16x8b __attribute__((ext_vector_type(8)));  // builtin operand type

__device__ __forceinline__ float rcp_(float x) {
#if __has_builtin(__builtin_amdgcn_rcpf)
    return __builtin_amdgcn_rcpf(x);
#else
    return 1.0f / x;
#endif
}
__device__ __forceinline__ float sigmoid_(float x) {
    return rcp_(1.0f + __expf(-x));
}
__device__ __forceinline__ float tanh_(float x) {
    float ax = fabsf(x);
    float r  = __expf(-2.0f * ax);
    float t  = (1.0f - r) * rcp_(1.0f + r);
    return x < 0.0f ? -t : t;
}
// f32 -> bf16 bits, round-to-nearest-even
__device__ __forceinline__ short f2bf(float f) {
    uint32_t u = __builtin_bit_cast(uint32_t, f);
    u = (u + 0x7FFFu + ((u >> 16) & 1u)) >> 16;
    return (short)(u & 0xFFFFu);
}

// LDS-only barrier (composable_kernel block_sync_lds pattern): waits LDS ops,
// does NOT drain vmcnt -> global stores + prefetch loads stay in flight.
__device__ __forceinline__ void lds_sync() {
    asm volatile("s_waitcnt lgkmcnt(0)\n\ts_barrier" ::: "memory");
}

// ---------------------------------------------------------------------------
// ws layout:
//   floats [0 .. 32768)     : state: [0]=cph,[1]=cpc,[2]=hph,[3]=hpc (64,128)
//   shorts [65536 .. 98304) : Wbf [gate*128+col][k] bf16, gate 0=Wc 1=Wo
// ---------------------------------------------------------------------------

// Kernel 1: collapsed tree state. Wi/Wf/Wu columns preloaded to registers;
// k-split 4-way across 512 threads with LDS partial reduction; wprep fused.
__global__ __launch_bounds__(512)
void state_kernel(const float* __restrict__ root_c, const float* __restrict__ root_h,
                  const float* __restrict__ Wi, const float* __restrict__ bi,
                  const float* __restrict__ Wf, const float* __restrict__ bfv,
                  const float* __restrict__ Wu, const float* __restrict__ bu,
                  const float* __restrict__ Wc, const float* __restrict__ bc,
                  const float* __restrict__ Wo, const float* __restrict__ bo,
                  float* __restrict__ ws, short* __restrict__ wbf)
{
    const int b   = blockIdx.x;
    const int tid = threadIdx.x;
    const int m   = tid & 127;
    const int q   = tid >> 7;            // 0..3
    const int k0  = q * 32;

    __shared__ float h_sh[Mm];
    __shared__ float c_sh[Mm];
    __shared__ float part[4][4][Mm];     // [slot][q][m]

    // fused wprep: 64 blocks x 512 threads = 32768 elems, 1 per thread
    {
        int idx  = b * 512 + tid;
        int gate = idx >> 14;
        int col  = (idx >> 7) & 127;
        int k    = idx & 127;
        const float* W = gate ? Wo : Wc;
        wbf[idx] = f2bf(W[k * Mm + col]);
    }

    // preload my k-slice of Wi/Wf/Wu columns (coalesced across m)
    float wi[32], wf[32], wu[32];
    #pragma unroll
    for (int kk = 0; kk < 32; ++kk) {
        wi[kk] = Wi[(k0 + kk) * Mm + m];
        wf[kk] = Wf[(k0 + kk) * Mm + m];
        wu[kk] = Wu[(k0 + kk) * Mm + m];
    }

    float c = 0.f;
    if (q == 0) {
        c = root_c[b * Mm + m];
        h_sh[m] = root_h[b * Mm + m];
    }
    __syncthreads();

    const float bi_m = bi[m], bf_m = bfv[m], bu_m = bu[m];

    for (int it = 0; it < 10; ++it) {        // depth-1 = 10
        float di0 = 0.f, di1 = 0.f, df0 = 0.f, df1 = 0.f, du0 = 0.f, du1 = 0.f;
        #pragma unroll
        for (int kk = 0; kk < 32; kk += 2) {
            float h0 = h_sh[k0 + kk], h1 = h_sh[k0 + kk + 1];
            di0 = fmaf(h0, wi[kk], di0);
            di1 = fmaf(h1, wi[kk + 1], di1);
            df0 = fmaf(h0, wf[kk], df0);
            df1 = fmaf(h1, wf[kk + 1], df1);
            du0 = fmaf(h0, wu[kk], du0);
            du1 = fmaf(h1, wu[kk + 1], du1);
        }
        part[0][q][m] = di0 + di1;
        part[1][q][m] = df0 + df1;
        part[2][q][m] = du0 + du1;
        __syncthreads();
        if (q == 0) {
            float di = (part[0][0][m] + part[0][1][m]) + (part[0][2][m] + part[0][3][m]);
            float df = (part[1][0][m] + part[1][1][m]) + (part[1][2][m] + part[1][3][m]);
            float du = (part[2][0][m] + part[2][1][m]) + (part[2][2][m] + part[2][3][m]);
            float ig = sigmoid_(di + bi_m);
            float fg = sigmoid_(df + bf_m);
            float ug = tanh_(du + bu_m);
            c = ig * ug + fg * c;
            h_sh[m] = tanh_(c);
        }
        __syncthreads();
    }
    if (q == 0) c_sh[m] = c;
    __syncthreads();

    // leaf on final h and c states, k-split
    float dch = 0.f, doh = 0.f, dcc = 0.f, doc = 0.f;
    #pragma unroll
    for (int kk = 0; kk < 32; ++kk) {
        int k = k0 + kk;
        float hk = h_sh[k], ck = c_sh[k];
        float wc = Wc[k * Mm + m], wo = Wo[k * Mm + m];
        dch = fmaf(hk, wc, dch);
        doh = fmaf(hk, wo, doh);
        dcc = fmaf(ck, wc, dcc);
        doc = fmaf(ck, wo, doc);
    }
    part[0][q][m] = dch;
    part[1][q][m] = doh;
    part[2][q][m] = dcc;
    part[3][q][m] = doc;
    __syncthreads();
    if (q == 0) {
        float Dch = (part[0][0][m] + part[0][1][m]) + (part[0][2][m] + part[0][3][m]);
        float Doh = (part[1][0][m] + part[1][1][m]) + (part[1][2][m] + part[1][3][m]);
        float Dcc = (part[2][0][m] + part[2][1][m]) + (part[2][2][m] + part[2][3][m]);
        float Doc = (part[3][0][m] + part[3][1][m]) + (part[3][2][m] + part[3][3][m]);
        const float bcm = bc[m], bom = bo[m];
        float cph = Dch + bcm;
        float cpc = Dcc + bcm;
        float hph = sigmoid_(Doh + bom) * tanh_(cph);
        float hpc = sigmoid_(Doc + bom) * tanh_(cpc);
        ws[0 * Bb * Mm + b * Mm + m] = cph;
        ws[1 * Bb * Mm + b * Mm + m] = cpc;
        ws[2 * Bb * Mm + b * Mm + m] = hph;
        ws[3 * Bb * Mm + b * Mm + m] = hpc;
    }
}

// ---------------------------------------------------------------------------
// Kernel 2 (R7 best-known, verbatim): 1024 blocks x 512 thr, 2 tiles of 64
// rows/block, A double-buffered in LDS, unified full-row epilogue (each row's
// 3KB written once, ascending). All syncs lgkm-only.
// ---------------------------------------------------------------------------
__global__ __launch_bounds__(512, 4)
void fused_kernel(const float* __restrict__ embs,
                  const short* __restrict__ wbf,
                  const float* __restrict__ bc, const float* __restrict__ bo,
                  const float* __restrict__ state,
                  float* __restrict__ out)
{
    // A0[64][LDA]bf16 | A1[64][LDA]bf16 | ce[32][LDF]f32 | he[32][LDF]f32 | st[4][128]
    __shared__ __align__(16) char smem[70656];
    short* A0   = (short*)smem;                    // 17408 B
    short* A1   = (short*)(smem + 17408);          // 17408 B
    float* ce_l = (float*)(smem + 34816);          // 16896 B
    float* he_l = (float*)(smem + 51712);          // 16896 B
    float* st_l = (float*)(smem + 68608);          // 2048 B

    const int tid  = threadIdx.x;
    const int w    = tid >> 6;          // wave 0..7
    const int lane = tid & 63;
    const int g    = lane >> 4;         // lane group 0..3
    const int ln   = lane & 15;
    const int n0   = w * 16 + ln;       // output col 0..127
    const int rowbase0 = blockIdx.x * 128;
    const int rowbase1 = rowbase0 + 64;
    const int b        = rowbase0 >> 11;   // 128 | 2048, never spans batches

    // --- B fragments + biases + state stash (fly during staging) -----------
    bf16x8 bfrag[2][4];                 // [gate][ks], k = ks*32 + g*8 + j
    #pragma unroll
    for (int gate = 0; gate < 2; ++gate)
        #pragma unroll
        for (int ks = 0; ks < 4; ++ks)
            bfrag[gate][ks] = *(const bf16x8*)(
                wbf + gate * (Mm * Mm) + n0 * Mm + ks * 32 + g * 8);
    const float biasc = bc[n0];
    const float biaso = bo[n0];
    st_l[tid] = state[(tid >> 7) * (Bb * Mm) + b * Mm + (tid & 127)];

    // helpers ---------------------------------------------------------------
    auto stage_load = [&](int rowbase, f32x4 (&r)[4]) {
        #pragma unroll
        for (int i = 0; i < 4; ++i) {
            int idx = tid + 512 * i;            // 0..2047 float4-slots
            int rr  = idx >> 5;
            int kq  = idx & 31;
            r[i] = __builtin_nontemporal_load(
                (const f32x4*)(embs + (size_t)(rowbase + rr) * Mm + kq * 4));
        }
    };
    auto stage_write = [&](short* A, const f32x4 (&r)[4]) {
        #pragma unroll
        for (int i = 0; i < 4; ++i) {
            int idx = tid + 512 * i;
            int rr  = idx >> 5;
            int kq  = idx & 31;
            short4v s4;
            s4[0] = f2bf(r[i][0]); s4[1] = f2bf(r[i][1]);
            s4[2] = f2bf(r[i][2]); s4[3] = f2bf(r[i][3]);
            *(short4v*)(&A[rr * LDA + kq * 4]) = s4;
        }
    };
    auto do_mfma = [&](const short* A, f32x4 (&acc)[4][2]) {
        #pragma unroll
        for (int rt = 0; rt < 4; ++rt)
            #pragma unroll
            for (int gate = 0; gate < 2; ++gate) {
                float bv = gate ? biaso : biasc;
                acc[rt][gate][0] = bv; acc[rt][gate][1] = bv;
                acc[rt][gate][2] = bv; acc[rt][gate][3] = bv;
            }
        #pragma unroll
        for (int ks = 0; ks < 4; ++ks) {
            bf16x8 af[4];
            #pragma unroll
            for (int rt = 0; rt < 4; ++rt)
                af[rt] = *(const bf16x8*)(&A[(rt * 16 + ln) * LDA + ks * 32 + g * 8]);
            #pragma unroll
            for (int rt = 0; rt < 4; ++rt)
                #pragma unroll
                for (int gate = 0; gate < 2; ++gate)
                    acc[rt][gate] = __builtin_amdgcn_mfma_f32_16x16x32_bf16(
                        __builtin_bit_cast(bf16x8b, af[rt]),
                        __builtin_bit_cast(bf16x8b, bfrag[gate][ks]),
                        acc[rt][gate], 0, 0, 0);
        }
    };
    // epilogue: D layout col = lane&15 (= n0), row = 4*(lane>>4) + reg;
    // unified full-row writes: every row's 3KB stored once, ascending order.
    auto epilogue = [&](int rowbase, f32x4 (&acc)[4][2]) {
        #pragma unroll
        for (int half = 0; half < 2; ++half) {
            #pragma unroll
            for (int qq = 0; qq < 2; ++qq) {
                int rt = half * 2 + qq;
                #pragma unroll
                for (int r = 0; r < 4; ++r) {
                    int rowL = qq * 16 + g * 4 + r;      // 0..31 in this half
                    float cv = acc[rt][0][r];
                    float hv = sigmoid_(acc[rt][1][r]) * tanh_(cv);
                    ce_l[rowL * LDF + n0] = cv;
                    he_l[rowL * LDF + n0] = hv;
                }
            }
            lds_sync();
            // 32 rows x 192 f32x4 = 6144 units; 12/thread; lanes contiguous
            #pragma unroll
            for (int i = 0; i < 12; ++i) {
                int u  = tid + 512 * i;
                int rg = u / 192;
                int s  = u - rg * 192;      // f32x4 col in row, 0..191
                int sec = s >> 5;           // 0:ce 1:cph 2:cpc 3:he 4:hph 5:hpc
                int cc  = s & 31;
                const float* src =
                    (sec == 0) ? (ce_l + rg * LDF + cc * 4) :
                    (sec == 3) ? (he_l + rg * LDF + cc * 4) :
                    (st_l + ((sec < 3) ? (sec - 1) : (sec - 2)) * 128 + cc * 4);
                f32x4 v = *(const f32x4*)src;
                *(f32x4*)(out + (size_t)(rowbase + half * 32 + rg) * OUTC + s * 4) = v;
            }
            lds_sync();                     // LDS reads done before reuse
        }
    };

    // --- pipeline ----------------------------------------------------------
    f32x4 r0[4], r1[4];
    f32x4 acc[4][2];

    stage_load(rowbase0, r0);
    stage_write(A0, r0);
    lds_sync();                             // A0 visible (LDS-only wait)

    stage_load(rowbase1, r1);               // t1 reads in flight under t0 work

    do_mfma(A0, acc);
    stage_write(A1, r1);                    // reg-use vmcnt wait sits here
    lds_sync();                             // A0 reads done; A1 visible

    epilogue(rowbase0, acc);                // stores stream, no vmcnt drain
    do_mfma(A1, acc);
    epilogue(rowbase1, acc);
}

extern "C" void kernel_launch(void* const* d_in, const int* in_sizes, int n_in,
                              void* d_out, int out_size, void* d_ws, size_t ws_size,
                              hipStream_t stream) {
    const float* embs   = (const float*)d_in[0];
    const float* root_c = (const float*)d_in[1];
    const float* root_h = (const float*)d_in[2];
    const float* Wi = (const float*)d_in[3];
    const float* bi = (const float*)d_in[4];
    const float* Wf = (const float*)d_in[5];
    const float* bfv= (const float*)d_in[6];
    const float* Wu = (const float*)d_in[7];
    const float* bu = (const float*)d_in[8];
    const float* Wc = (const float*)d_in[9];
    const float* bc = (const float*)d_in[10];
    const float* Wo = (const float*)d_in[11];
    const float* bo = (const float*)d_in[12];

    float* out   = (float*)d_out;
    float* state = (float*)d_ws;                       // 128 KB
    short* wbf   = (short*)d_ws + 65536;               // 64 KB bf16 W

    state_kernel<<<dim3(Bb), dim3(512), 0, stream>>>(
        root_c, root_h, Wi, bi, Wf, bfv, Wu, bu, Wc, bc, Wo, bo, state, wbf);
    fused_kernel<<<dim3(1024), dim3(512), 0, stream>>>(
        embs, wbf, bc, bo, state, out);
}